// Round 14
// baseline (82.211 us; speedup 1.0000x reference)
//
#include <hip/hip_runtime.h>

#define N_NODES 50000
#define F_IN    512
#define F_OUT   96
#define N_EDGES 800000

#define RPB    128                          // rows per coarse bucket
#define NBKT   391                          // ceil(50000/128)
#define CAP    2560                         // bucket capacity (mean 2048, +11 sigma)
#define ECHUNK 4096
#define NCHUNK ((N_EDGES + ECHUNK - 1) / ECHUNK)   // 196
#define GEMM_BLOCKS ((N_NODES + 63) / 64)          // 782

typedef __attribute__((ext_vector_type(8))) short bf16x8;
typedef __attribute__((ext_vector_type(4))) float f32x4;

// f32 -> bf16 round-to-nearest-even (bit pattern)
__device__ __forceinline__ unsigned short f2bf(float f) {
    unsigned int u = __float_as_uint(f);
    unsigned int r = (u + 0x7FFFu + ((u >> 16) & 1u)) >> 16;
    return (unsigned short)r;
}
__device__ __forceinline__ float bf2f(unsigned short h) {
    return __uint_as_float(((unsigned int)h) << 16);
}

// ---------------------------------------------------------------------------
// Weight cast (+ fused bcnt-zero): w[512][96] f32 -> wTq fragment-major bf16:
// linear index i = ((((p*6+t)*2+ks)*64 + lane)*8 + j), lane = kg*16+lr,
// value = w[k][n] with n = t*16+lr, k = p*64+ks*32+kg*8+j.
// A wave's B-fragment load for (p,t,ks) is then ONE coalesced 1 KB block.
// ---------------------------------------------------------------------------
__global__ __launch_bounds__(256) void k_wcast(const float* __restrict__ w,
                                               unsigned short* __restrict__ wTq,
                                               int* __restrict__ bcnt) {
    if (blockIdx.x == 0) {
        const int t = threadIdx.x;
        bcnt[t] = 0;                       // 0..255
        if (t < 144) bcnt[256 + t] = 0;    // 256..399
    }
    const int i = blockIdx.x * 256 + threadIdx.x;
    if (i < F_OUT * F_IN) {
        const int j    = i & 7;
        const int lane = (i >> 3) & 63;
        const int ks   = (i >> 9) & 1;
        const int tp   = i >> 10;          // 0..47
        const int t    = tp % 6;
        const int p    = tp / 6;
        const int lr   = lane & 15;
        const int kg   = lane >> 4;
        const int n    = t * 16 + lr;
        const int k    = p * 64 + ks * 32 + kg * 8 + j;
        wTq[i] = f2bf(w[(size_t)k * F_OUT + n]);
    }
}

// ---------------------------------------------------------------------------
// FUSED: blocks [0, NCHUNK) = edge multisplit fill; rest = MFMA GEMM.
// GEMM v5 (TLP regime): LDS = 16 KB only (A dbuf, bf16, swizzled); B read
// per-MFMA as coalesced 1 KB global loads from L2-resident wTq (no LDS, no
// barrier for B). ~7 blocks/CU co-resident -> barrier drains hidden by other
// blocks' waves (m114 implicit overlap). Plain loads; no asm pinning.
// ---------------------------------------------------------------------------
__global__ __launch_bounds__(256) void k_fused(const float* __restrict__ x,
                                               const unsigned short* __restrict__ wTq,
                                               unsigned short* __restrict__ support,
                                               const int* __restrict__ erow,
                                               const int* __restrict__ ecol,
                                               const float* __restrict__ eval,
                                               int* __restrict__ bcnt,
                                               float2* __restrict__ bucket) {
    __shared__ __align__(16) char smem[16384];   // GEMM: 2 x 8 KB A tiles
    const int tid = threadIdx.x;

    if (blockIdx.x < NCHUNK) {
        // ---------------- fill path (uses 4.8 KB of smem) ----------------
        int* hist  = (int*)smem;          // [NBKT]
        int* gbase = hist + 400;          // [NBKT]
        int* lcur  = gbase + 400;         // [NBKT]
        for (int i = tid; i < NBKT; i += 256) { hist[i] = 0; lcur[i] = 0; }
        __syncthreads();

        const int base = blockIdx.x * ECHUNK;
        const int n = min(ECHUNK, N_EDGES - base);

        for (int i = tid; i < n; i += 256)
            atomicAdd(&hist[erow[base + i] >> 7], 1);
        __syncthreads();

        for (int b = tid; b < NBKT; b += 256)
            gbase[b] = hist[b] ? atomicAdd(&bcnt[b], hist[b]) : 0;
        __syncthreads();

        for (int i = tid; i < n; i += 256) {
            const int r = erow[base + i];
            const int b = r >> 7;
            const int pos = gbase[b] + atomicAdd(&lcur[b], 1);
            if (pos >= 0 && pos < CAP)
                bucket[(size_t)b * CAP + pos] = make_float2(
                    __int_as_float(((r & 127) << 16) | ecol[base + i]),
                    eval[base + i]);
        }
        return;
    }

    // ---------------- GEMM path ----------------
    unsigned short (*sX)[64 * 64] = (unsigned short (*)[64 * 64])smem;  // 2 x 8 KB

    const int lane = tid & 63;
    const int wave = tid >> 6;
    const int r0   = (blockIdx.x - NCHUNK) * 64;
    const int lr   = lane & 15;        // A-row (in wave tile) / B-col / C-col
    const int kg   = lane >> 4;        // k-group 0..3

    f32x4 acc[6];
    #pragma unroll
    for (int t = 0; t < 6; ++t) acc[t] = (f32x4){0.f, 0.f, 0.f, 0.f};

    float4 xr[4];   // in-flight A staging registers (one panel)

    auto XLOAD = [&](int p) {
        #pragma unroll
        for (int i = 0; i < 4; ++i) {
            const int chunk = i * 256 + tid;       // 0..1023
            const int row   = chunk >> 4;          // 0..63
            const int c     = chunk & 15;          // float4 index in row
            int gr = r0 + row;
            if (gr > N_NODES - 1) gr = N_NODES - 1;   // clamp: dup row, store-masked
            xr[i] = *reinterpret_cast<const float4*>(x + (size_t)gr * F_IN + p * 64 + c * 4);
        }
    };
    auto XWRITE = [&](int buf) {
        char* xb = (char*)&sX[buf][0];
        #pragma unroll
        for (int i = 0; i < 4; ++i) {
            const int chunk = i * 256 + tid;
            const int row   = chunk >> 4;
            const int c     = chunk & 15;
            ushort4 h;
            h.x = f2bf(xr[i].x); h.y = f2bf(xr[i].y);
            h.z = f2bf(xr[i].z); h.w = f2bf(xr[i].w);
            const int byte = (c * 8) ^ ((row & 7) << 4);
            *reinterpret_cast<ushort4*>(xb + row * 128 + byte) = h;
        }
    };
    auto COMPUTE = [&](int buf, int p) {
        const char* xb = (const char*)&sX[buf][0];
        const int xrow = wave * 16 + lr;
        // wave's B-fragment base: coalesced 1 KB per (p,t,ks), lane-linear
        const unsigned short* bbase = wTq + ((size_t)p * 12) * 512 + lane * 8;
        #pragma unroll
        for (int ks = 0; ks < 2; ++ks) {
            const int off = (ks * 64 + kg * 16) ^ ((xrow & 7) << 4);
            const bf16x8 af = *reinterpret_cast<const bf16x8*>(xb + xrow * 128 + off);
            #pragma unroll
            for (int t = 0; t < 6; ++t) {
                const bf16x8 bq = *reinterpret_cast<const bf16x8*>(
                    bbase + (t * 2 + ks) * 512);
                acc[t] = __builtin_amdgcn_mfma_f32_16x16x32_bf16(af, bq, acc[t], 0, 0, 0);
            }
        }
    };

    XLOAD(0);
    XWRITE(0);
    __syncthreads();
    for (int p = 0; p < 8; ++p) {
        if (p < 7) XLOAD(p + 1);        // issue next panel's loads early
        COMPUTE(p & 1, p);              // MFMAs + coalesced B loads hide them
        if (p < 7) XWRITE((p + 1) & 1); // write late (T14)
        __syncthreads();                // one barrier per panel
    }

    // ---- store (bf16): C col = lr, row = kg*4 + reg ----
    #pragma unroll
    for (int t = 0; t < 6; ++t) {
        #pragma unroll
        for (int r = 0; r < 4; ++r) {
            const int row = r0 + wave * 16 + kg * 4 + r;
            if (row < N_NODES)
                support[(size_t)row * F_OUT + t * 16 + lr] = f2bf(acc[t][r]);
        }
    }
}

// ---------------------------------------------------------------------------
// S: in-bucket row sort -> bucket2 (fixed-cap layout) + per-row offsets.
// rowOffs layout: [b*129 + 0..127] = row bases, [b*129 + 128] = bucket end.
// ---------------------------------------------------------------------------
__global__ __launch_bounds__(256) void kS_sort(const int* __restrict__ bcnt,
                                               const float2* __restrict__ bucket,
                                               float2* __restrict__ bucket2,
                                               int* __restrict__ rowOffs) {
    __shared__ int cnt[RPB];
    __shared__ int sc[RPB];
    __shared__ int rbase[RPB];
    __shared__ int rcur[RPB];
    const int b   = blockIdx.x;
    const int tid = threadIdx.x;

    if (tid < RPB) { cnt[tid] = 0; rcur[tid] = 0; }
    __syncthreads();

    const int beg = b * CAP;
    const int n   = min(bcnt[b], CAP);

    for (int i = tid; i < n; i += 256)
        atomicAdd(&cnt[(__float_as_int(bucket[beg + i].x) >> 16) & 127], 1);
    __syncthreads();

    if (tid < RPB) sc[tid] = cnt[tid];
    __syncthreads();
    #pragma unroll
    for (int off = 1; off < RPB; off <<= 1) {
        int a = 0;
        if (tid < RPB && tid >= off) a = sc[tid - off];
        __syncthreads();
        if (tid < RPB) sc[tid] += a;
        __syncthreads();
    }
    if (tid < RPB) {
        const int rb = beg + sc[tid] - cnt[tid];   // exclusive
        rbase[tid] = rb;
        rowOffs[b * 129 + tid] = rb;
    }
    if (tid == RPB) rowOffs[b * 129 + RPB] = beg + n;
    __syncthreads();

    for (int i = tid; i < n; i += 256) {
        const float2 ev  = bucket[beg + i];
        const int    key = __float_as_int(ev.x);
        const int    r   = (key >> 16) & 127;
        const int    pos = rbase[r] + atomicAdd(&rcur[r], 1);
        bucket2[pos] = make_float2(__int_as_float(key & 0xFFFF), ev.y);
    }
}

// ---------------------------------------------------------------------------
// Gather: thread = (row, f16), f16 in [0,6) -> 16 features. bf16 support.
// Register accumulate, fused ReLU, single write. No atomics.
// ---------------------------------------------------------------------------
__global__ __launch_bounds__(256) void k_gather(const int* __restrict__ rowOffs,
                                                const float2* __restrict__ bucket2,
                                                const unsigned short* __restrict__ support,
                                                float* __restrict__ out) {
    const int gid = blockIdx.x * 256 + threadIdx.x;
    if (gid >= N_NODES * 6) return;
    const int r   = gid / 6;
    const int f16 = gid - r * 6;

    const int idx = (r >> 7) * 129 + (r & 127);
    const int beg = rowOffs[idx];
    const int end = rowOffs[idx + 1];

    float acc[16];
    #pragma unroll
    for (int j = 0; j < 16; ++j) acc[j] = 0.f;

    for (int i = beg; i < end; ++i) {
        const float2 cv = bucket2[i];
        const int   c = __float_as_int(cv.x);
        const float v = cv.y;
        const unsigned short* sp = support + (size_t)c * F_OUT + f16 * 16;
        const bf16x8 s0 = *reinterpret_cast<const bf16x8*>(sp);
        const bf16x8 s1 = *reinterpret_cast<const bf16x8*>(sp + 8);
        #pragma unroll
        for (int j = 0; j < 8; ++j) {
            acc[j]     = fmaf(v, bf2f((unsigned short)s0[j]), acc[j]);
            acc[8 + j] = fmaf(v, bf2f((unsigned short)s1[j]), acc[8 + j]);
        }
    }

    float* o = out + (size_t)r * F_OUT + f16 * 16;
    #pragma unroll
    for (int q = 0; q < 4; ++q) {
        float4 ov;
        ov.x = fmaxf(acc[q * 4 + 0], 0.f);
        ov.y = fmaxf(acc[q * 4 + 1], 0.f);
        ov.z = fmaxf(acc[q * 4 + 2], 0.f);
        ov.w = fmaxf(acc[q * 4 + 3], 0.f);
        *reinterpret_cast<float4*>(o + q * 4) = ov;
    }
}

extern "C" void kernel_launch(void* const* d_in, const int* in_sizes, int n_in,
                              void* d_out, int out_size, void* d_ws, size_t ws_size,
                              hipStream_t stream) {
    const float* x    = (const float*)d_in[0];
    const int*   erow = (const int*)d_in[1];
    const int*   ecol = (const int*)d_in[2];
    const float* eval = (const float*)d_in[3];
    const float* w    = (const float*)d_in[4];
    float*       out  = (float*)d_out;

    // workspace layout (bytes from d_ws):
    unsigned short* support = (unsigned short*)d_ws;               // 9.6 MB
    int*    bcnt    = (int*)((char*)d_ws + 9600000);               // [391] pad 400
    int*    rowOffs = bcnt + 400;                                  // [50439] pad 50560
    unsigned short* wTq = (unsigned short*)(rowOffs + 50560);      // 49152 bf16
    float2* bucket  = (float2*)((char*)wTq + 98304);               // 8.0 MB
    float2* bucket2 = bucket + (size_t)NBKT * CAP;                 // 8.0 MB

    k_wcast<<<(F_OUT * F_IN + 255) / 256, 256, 0, stream>>>(w, wTq, bcnt);

    k_fused<<<NCHUNK + GEMM_BLOCKS, 256, 0, stream>>>(x, wTq, support,
                                                      erow, ecol, eval,
                                                      bcnt, bucket);

    kS_sort<<<NBKT, 256, 0, stream>>>(bcnt, bucket, bucket2, rowOffs);

    const int gthreads = N_NODES * 6;
    k_gather<<<(gthreads + 255) / 256, 256, 0, stream>>>(rowOffs, bucket2, support, out);
}

// Round 15
// 82.091 us; speedup vs baseline: 1.0015x; 1.0015x over previous
//
#include <hip/hip_runtime.h>

#define N_NODES 50000
#define F_IN    512
#define F_OUT   96
#define N_EDGES 800000

#define RPB    128                          // rows per coarse bucket
#define NBKT   391                          // ceil(50000/128)
#define CAP    2560                         // bucket capacity (mean 2048, +11 sigma)
#define ECHUNK 4096
#define NCHUNK ((N_EDGES + ECHUNK - 1) / ECHUNK)   // 196
#define GEMM_BLOCKS ((N_NODES + 63) / 64)          // 782

typedef __attribute__((ext_vector_type(8))) short bf16x8;
typedef __attribute__((ext_vector_type(4))) float f32x4;

// f32 -> bf16 round-to-nearest-even (bit pattern)
__device__ __forceinline__ unsigned short f2bf(float f) {
    unsigned int u = __float_as_uint(f);
    unsigned int r = (u + 0x7FFFu + ((u >> 16) & 1u)) >> 16;
    return (unsigned short)r;
}
__device__ __forceinline__ float bf2f(unsigned short h) {
    return __uint_as_float(((unsigned int)h) << 16);
}

// ---------------------------------------------------------------------------
// Weight cast (+ fused bcnt-zero): w[512][96] f32 -> wTq fragment-major bf16:
// i = ((((p*6+t)*2+ks)*64 + lane)*8 + j), lane = kg*16+lr,
// value = w[k][n], n = t*16+lr, k = p*64+ks*32+kg*8+j.
// A wave's B-fragment load for (p,t,ks) is ONE coalesced 1 KB block.
// ---------------------------------------------------------------------------
__global__ __launch_bounds__(256) void k_wcast(const float* __restrict__ w,
                                               unsigned short* __restrict__ wTq,
                                               int* __restrict__ bcnt) {
    if (blockIdx.x == 0) {
        const int t = threadIdx.x;
        bcnt[t] = 0;                       // 0..255
        if (t < 144) bcnt[256 + t] = 0;    // 256..399
    }
    const int i = blockIdx.x * 256 + threadIdx.x;
    if (i < F_OUT * F_IN) {
        const int j    = i & 7;
        const int lane = (i >> 3) & 63;
        const int ks   = (i >> 9) & 1;
        const int tp   = i >> 10;          // 0..47
        const int t    = tp % 6;
        const int p    = tp / 6;
        const int lr   = lane & 15;
        const int kg   = lane >> 4;
        const int n    = t * 16 + lr;
        const int k    = p * 64 + ks * 32 + kg * 8 + j;
        wTq[i] = f2bf(w[(size_t)k * F_OUT + n]);
    }
}

// ---------------------------------------------------------------------------
// FUSED (512 threads/block): blocks [0, NCHUNK) = edge fill; rest = GEMM.
// GEMM v6 (N-split TLP): 8 waves/block; wave = 16 rows x 48 cols
// (wr = wave&3 row-group, wc = wave>>2 col-group). A staged once in
// 2 x 8 KB LDS shared by both col-groups; B per-MFMA coalesced 1 KB loads
// from L2-resident wTq. 6256 waves -> ~24-30 waves/CU (2x R14) so the
// per-panel barrier drains are covered by TLP. acc = 3 tiles = 12 VGPR.
// ---------------------------------------------------------------------------
__global__ __launch_bounds__(512) void k_fused(const float* __restrict__ x,
                                               const unsigned short* __restrict__ wTq,
                                               unsigned short* __restrict__ support,
                                               const int* __restrict__ erow,
                                               const int* __restrict__ ecol,
                                               const float* __restrict__ eval,
                                               int* __restrict__ bcnt,
                                               float2* __restrict__ bucket) {
    __shared__ __align__(16) char smem[16384];   // GEMM: 2 x 8 KB A tiles
    const int tid = threadIdx.x;

    if (blockIdx.x < NCHUNK) {
        // ---------------- fill path (4.8 KB of smem) ----------------
        int* hist  = (int*)smem;          // [NBKT]
        int* gbase = hist + 400;          // [NBKT]
        int* lcur  = gbase + 400;         // [NBKT]
        for (int i = tid; i < NBKT; i += 512) { hist[i] = 0; lcur[i] = 0; }
        __syncthreads();

        const int base = blockIdx.x * ECHUNK;
        const int n = min(ECHUNK, N_EDGES - base);

        for (int i = tid; i < n; i += 512)
            atomicAdd(&hist[erow[base + i] >> 7], 1);
        __syncthreads();

        for (int b = tid; b < NBKT; b += 512)
            gbase[b] = hist[b] ? atomicAdd(&bcnt[b], hist[b]) : 0;
        __syncthreads();

        for (int i = tid; i < n; i += 512) {
            const int r = erow[base + i];
            const int b = r >> 7;
            const int pos = gbase[b] + atomicAdd(&lcur[b], 1);
            if (pos >= 0 && pos < CAP)
                bucket[(size_t)b * CAP + pos] = make_float2(
                    __int_as_float(((r & 127) << 16) | ecol[base + i]),
                    eval[base + i]);
        }
        return;
    }

    // ---------------- GEMM path ----------------
    unsigned short (*sX)[64 * 64] = (unsigned short (*)[64 * 64])smem;  // 2 x 8 KB

    const int lane = tid & 63;
    const int wave = tid >> 6;         // 0..7
    const int wr   = wave & 3;         // row group (16 rows)
    const int wc   = wave >> 2;        // col group (48 cols)
    const int r0   = (blockIdx.x - NCHUNK) * 64;
    const int lr   = lane & 15;
    const int kg   = lane >> 4;

    f32x4 acc[3];
    #pragma unroll
    for (int t = 0; t < 3; ++t) acc[t] = (f32x4){0.f, 0.f, 0.f, 0.f};

    float4 xr[2];   // A staging: 1024 chunks / 512 threads = 2 each

    auto XLOAD = [&](int p) {
        #pragma unroll
        for (int i = 0; i < 2; ++i) {
            const int chunk = i * 512 + tid;       // 0..1023
            const int row   = chunk >> 4;          // 0..63
            const int c     = chunk & 15;          // float4 index in row
            int gr = r0 + row;
            if (gr > N_NODES - 1) gr = N_NODES - 1;   // clamp: dup row, store-masked
            xr[i] = *reinterpret_cast<const float4*>(x + (size_t)gr * F_IN + p * 64 + c * 4);
        }
    };
    auto XWRITE = [&](int buf) {
        char* xb = (char*)&sX[buf][0];
        #pragma unroll
        for (int i = 0; i < 2; ++i) {
            const int chunk = i * 512 + tid;
            const int row   = chunk >> 4;
            const int c     = chunk & 15;
            ushort4 h;
            h.x = f2bf(xr[i].x); h.y = f2bf(xr[i].y);
            h.z = f2bf(xr[i].z); h.w = f2bf(xr[i].w);
            const int byte = (c * 8) ^ ((row & 7) << 4);
            *reinterpret_cast<ushort4*>(xb + row * 128 + byte) = h;
        }
    };
    auto COMPUTE = [&](int buf, int p) {
        const char* xb = (const char*)&sX[buf][0];
        const int xrow = wr * 16 + lr;
        // wave's B base: fragments (p, wc*3+t, ks), lane-linear 1 KB each
        const unsigned short* bbase = wTq + ((size_t)p * 12 + wc * 6) * 512 + lane * 8;
        #pragma unroll
        for (int ks = 0; ks < 2; ++ks) {
            const int off = (ks * 64 + kg * 16) ^ ((xrow & 7) << 4);
            const bf16x8 af = *reinterpret_cast<const bf16x8*>(xb + xrow * 128 + off);
            #pragma unroll
            for (int t = 0; t < 3; ++t) {
                const bf16x8 bq = *reinterpret_cast<const bf16x8*>(
                    bbase + (t * 2 + ks) * 512);
                acc[t] = __builtin_amdgcn_mfma_f32_16x16x32_bf16(af, bq, acc[t], 0, 0, 0);
            }
        }
    };

    XLOAD(0);
    XWRITE(0);
    __syncthreads();
    for (int p = 0; p < 8; ++p) {
        if (p < 7) XLOAD(p + 1);        // issue next panel's loads early
        COMPUTE(p & 1, p);              // MFMAs + coalesced B loads
        if (p < 7) XWRITE((p + 1) & 1); // write late (T14)
        __syncthreads();                // one barrier per panel
    }

    // ---- store (bf16): col = wc*48 + t*16 + lr, row = wr*16 + kg*4 + r ----
    #pragma unroll
    for (int t = 0; t < 3; ++t) {
        #pragma unroll
        for (int r = 0; r < 4; ++r) {
            const int row = r0 + wr * 16 + kg * 4 + r;
            if (row < N_NODES)
                support[(size_t)row * F_OUT + wc * 48 + t * 16 + lr] = f2bf(acc[t][r]);
        }
    }
}

// ---------------------------------------------------------------------------
// S: in-bucket row sort -> bucket2 (fixed-cap layout) + per-row offsets.
// rowOffs layout: [b*129 + 0..127] = row bases, [b*129 + 128] = bucket end.
// ---------------------------------------------------------------------------
__global__ __launch_bounds__(256) void kS_sort(const int* __restrict__ bcnt,
                                               const float2* __restrict__ bucket,
                                               float2* __restrict__ bucket2,
                                               int* __restrict__ rowOffs) {
    __shared__ int cnt[RPB];
    __shared__ int sc[RPB];
    __shared__ int rbase[RPB];
    __shared__ int rcur[RPB];
    const int b   = blockIdx.x;
    const int tid = threadIdx.x;

    if (tid < RPB) { cnt[tid] = 0; rcur[tid] = 0; }
    __syncthreads();

    const int beg = b * CAP;
    const int n   = min(bcnt[b], CAP);

    for (int i = tid; i < n; i += 256)
        atomicAdd(&cnt[(__float_as_int(bucket[beg + i].x) >> 16) & 127], 1);
    __syncthreads();

    if (tid < RPB) sc[tid] = cnt[tid];
    __syncthreads();
    #pragma unroll
    for (int off = 1; off < RPB; off <<= 1) {
        int a = 0;
        if (tid < RPB && tid >= off) a = sc[tid - off];
        __syncthreads();
        if (tid < RPB) sc[tid] += a;
        __syncthreads();
    }
    if (tid < RPB) {
        const int rb = beg + sc[tid] - cnt[tid];   // exclusive
        rbase[tid] = rb;
        rowOffs[b * 129 + tid] = rb;
    }
    if (tid == RPB) rowOffs[b * 129 + RPB] = beg + n;
    __syncthreads();

    for (int i = tid; i < n; i += 256) {
        const float2 ev  = bucket[beg + i];
        const int    key = __float_as_int(ev.x);
        const int    r   = (key >> 16) & 127;
        const int    pos = rbase[r] + atomicAdd(&rcur[r], 1);
        bucket2[pos] = make_float2(__int_as_float(key & 0xFFFF), ev.y);
    }
}

// ---------------------------------------------------------------------------
// Gather: thread = (row, f16), f16 in [0,6) -> 16 features. bf16 support.
// Register accumulate, fused ReLU, single write. No atomics.
// ---------------------------------------------------------------------------
__global__ __launch_bounds__(256) void k_gather(const int* __restrict__ rowOffs,
                                                const float2* __restrict__ bucket2,
                                                const unsigned short* __restrict__ support,
                                                float* __restrict__ out) {
    const int gid = blockIdx.x * 256 + threadIdx.x;
    if (gid >= N_NODES * 6) return;
    const int r   = gid / 6;
    const int f16 = gid - r * 6;

    const int idx = (r >> 7) * 129 + (r & 127);
    const int beg = rowOffs[idx];
    const int end = rowOffs[idx + 1];

    float acc[16];
    #pragma unroll
    for (int j = 0; j < 16; ++j) acc[j] = 0.f;

    for (int i = beg; i < end; ++i) {
        const float2 cv = bucket2[i];
        const int   c = __float_as_int(cv.x);
        const float v = cv.y;
        const unsigned short* sp = support + (size_t)c * F_OUT + f16 * 16;
        const bf16x8 s0 = *reinterpret_cast<const bf16x8*>(sp);
        const bf16x8 s1 = *reinterpret_cast<const bf16x8*>(sp + 8);
        #pragma unroll
        for (int j = 0; j < 8; ++j) {
            acc[j]     = fmaf(v, bf2f((unsigned short)s0[j]), acc[j]);
            acc[8 + j] = fmaf(v, bf2f((unsigned short)s1[j]), acc[8 + j]);
        }
    }

    float* o = out + (size_t)r * F_OUT + f16 * 16;
    #pragma unroll
    for (int q = 0; q < 4; ++q) {
        float4 ov;
        ov.x = fmaxf(acc[q * 4 + 0], 0.f);
        ov.y = fmaxf(acc[q * 4 + 1], 0.f);
        ov.z = fmaxf(acc[q * 4 + 2], 0.f);
        ov.w = fmaxf(acc[q * 4 + 3], 0.f);
        *reinterpret_cast<float4*>(o + q * 4) = ov;
    }
}

extern "C" void kernel_launch(void* const* d_in, const int* in_sizes, int n_in,
                              void* d_out, int out_size, void* d_ws, size_t ws_size,
                              hipStream_t stream) {
    const float* x    = (const float*)d_in[0];
    const int*   erow = (const int*)d_in[1];
    const int*   ecol = (const int*)d_in[2];
    const float* eval = (const float*)d_in[3];
    const float* w    = (const float*)d_in[4];
    float*       out  = (float*)d_out;

    // workspace layout (bytes from d_ws):
    unsigned short* support = (unsigned short*)d_ws;               // 9.6 MB
    int*    bcnt    = (int*)((char*)d_ws + 9600000);               // [391] pad 400
    int*    rowOffs = bcnt + 400;                                  // [50439] pad 50560
    unsigned short* wTq = (unsigned short*)(rowOffs + 50560);      // 49152 bf16
    float2* bucket  = (float2*)((char*)wTq + 98304);               // 8.0 MB
    float2* bucket2 = bucket + (size_t)NBKT * CAP;                 // 8.0 MB

    k_wcast<<<(F_OUT * F_IN + 255) / 256, 256, 0, stream>>>(w, wTq, bcnt);

    k_fused<<<NCHUNK + GEMM_BLOCKS, 512, 0, stream>>>(x, wTq, support,
                                                      erow, ecol, eval,
                                                      bcnt, bucket);

    kS_sort<<<NBKT, 256, 0, stream>>>(bcnt, bucket, bucket2, rowOffs);

    const int gthreads = N_NODES * 6;
    k_gather<<<(gthreads + 255) / 256, 256, 0, stream>>>(rowOffs, bucket2, support, out);
}